// Round 8
// baseline (591.292 us; speedup 1.0000x reference)
//
#include <hip/hip_runtime.h>

// Luong 'general' attention, B=4 D=256 L=4096.
// K0 transpose/cast q,c -> [B][L][D] f16 ; K0b W f32->f16 ; K1 linear qw=q@W^T+b ;
// K0c context cast [B][D][L] f32->f16 (aliases qT16, dead after K1).
// K2a attn_lsum: 1024 blocks (o=32 x qh x b), 256thr, no LDS staging/barriers;
//      scores direct from L2-resident cT16 (bit-identical frags to K2b),
//      row sums of exp(s) -> lsum_ws[b][qh][o].
// K2b attn_pv: 512 blocks (o=64 x qh x b), 512thr, 2 blocks/CU (LDS 72KB);
//      scores A from DMA-staged c_lds (dbuf), w=exp(s)*invl -> f32x4 wgt
//      + f16x4 w_lds; PV A=w_lds b128, B direct from cD16; cross-oh obuf
//      (aliased on smem); out via 2-way deterministic atomicAdd onto memset-0.
// ws: 25.3 MB + 128KB lsum table.

#define BATCH 4
#define DDIM  256
#define LSEQ  4096
#define TQ    64

typedef float    f32x4 __attribute__((ext_vector_type(4)));
typedef _Float16 f16x8 __attribute__((ext_vector_type(8)));
typedef _Float16 f16x4 __attribute__((ext_vector_type(4)));

__device__ __forceinline__ void gld16(const void* g, void* l) {
  __builtin_amdgcn_global_load_lds((const __attribute__((address_space(1))) void*)g,
                                   (__attribute__((address_space(3))) void*)l, 16, 0, 0);
}

// ---------------- K0: [B][D][L] f32 -> [B][L][D] f16 (query & context) ------
__global__ __launch_bounds__(256) void transpose_cast(
    const float* __restrict__ q_in, const float* __restrict__ c_in,
    _Float16* __restrict__ q_out, _Float16* __restrict__ c_out)
{
  __shared__ float tile[64][68];
  const int which = blockIdx.z >> 2;
  const int b     = blockIdx.z & 3;
  const float* __restrict__ src = which ? c_in : q_in;
  _Float16* __restrict__ dst    = which ? c_out : q_out;
  const int l0 = blockIdx.x * 64, d0 = blockIdx.y * 64;
  const int tid = threadIdx.x;
  const int tr = tid >> 4, tc = (tid & 15) << 2;
#pragma unroll
  for (int i = 0; i < 4; ++i) {
    int d = tr + i * 16;
    f32x4 v = *(const f32x4*)(src + ((size_t)b * DDIM + d0 + d) * LSEQ + l0 + tc);
    *(f32x4*)&tile[d][tc] = v;
  }
  __syncthreads();
#pragma unroll
  for (int i = 0; i < 4; ++i) {
    int l = tr + i * 16;
    f16x4 h;
    h[0] = (_Float16)tile[tc + 0][l];
    h[1] = (_Float16)tile[tc + 1][l];
    h[2] = (_Float16)tile[tc + 2][l];
    h[3] = (_Float16)tile[tc + 3][l];
    *(f16x4*)(dst + ((size_t)b * LSEQ + l0 + l) * DDIM + d0 + tc) = h;
  }
}

// ---------------- K0b: W f32 -> f16 -----------------------------------------
__global__ __launch_bounds__(256) void wconv(const float* __restrict__ w,
                                             _Float16* __restrict__ w16) {
  int i = (blockIdx.x * 256 + threadIdx.x) * 4;
  f32x4 v = *(const f32x4*)(w + i);
  f16x4 h;
  h[0] = (_Float16)v[0]; h[1] = (_Float16)v[1];
  h[2] = (_Float16)v[2]; h[3] = (_Float16)v[3];
  *(f16x4*)(w16 + i) = h;
}

// ---------------- K0c: context [B][D][L] f32 -> f16 (same layout, pure cast)-
__global__ __launch_bounds__(256) void castD(const float* __restrict__ c_in,
                                             _Float16* __restrict__ cD16) {
  size_t i = ((size_t)blockIdx.x * 256 + threadIdx.x) * 8;
  f32x4 a = *(const f32x4*)(c_in + i);
  f32x4 b = *(const f32x4*)(c_in + i + 4);
  f16x8 h;
  h[0] = (_Float16)a[0]; h[1] = (_Float16)a[1];
  h[2] = (_Float16)a[2]; h[3] = (_Float16)a[3];
  h[4] = (_Float16)b[0]; h[5] = (_Float16)b[1];
  h[6] = (_Float16)b[2]; h[7] = (_Float16)b[3];
  *(f16x8*)(cD16 + i) = h;
}

// ---------------- K1: qw16 = qT16 @ W^T + bias ------------------------------
__global__ __launch_bounds__(256) void linear_q(
    const _Float16* __restrict__ qT16, const _Float16* __restrict__ W16,
    const float* __restrict__ bias, _Float16* __restrict__ qw16)
{
  const int tid = threadIdx.x;
  const int wv = tid >> 6, ln = tid & 63, g = ln >> 4, c16 = ln & 15;
  const size_t r0 = (size_t)blockIdx.x * 64 + wv * 16;

  f16x8 qa[8];
  const _Float16* qrow = qT16 + (r0 + c16) * DDIM + g * 8;
#pragma unroll
  for (int kk = 0; kk < 8; ++kk) qa[kk] = *(const f16x8*)(qrow + kk * 32);

  f32x4 acc[16];
#pragma unroll
  for (int n = 0; n < 16; ++n) acc[n] = f32x4{0.f, 0.f, 0.f, 0.f};

#pragma unroll 2
  for (int kk = 0; kk < 8; ++kk) {
#pragma unroll
    for (int n = 0; n < 16; ++n) {
      f16x8 bf = *(const f16x8*)(W16 + (n * 16 + c16) * DDIM + kk * 32 + g * 8);
      acc[n] = __builtin_amdgcn_mfma_f32_16x16x32_f16(qa[kk], bf, acc[n], 0, 0, 0);
    }
  }
#pragma unroll
  for (int n = 0; n < 16; ++n) {
    float bb = bias[n * 16 + c16];
#pragma unroll
    for (int r = 0; r < 4; ++r)
      qw16[(r0 + 4 * g + r) * DDIM + n * 16 + c16] = (_Float16)(acc[n][r] + bb);
  }
}

// ---------------- K2a: row sums of exp(scores) ------------------------------
// 1024 blocks: (otA in 0..127 -> 32 o) x (qh 0..1 -> 32 tiles) x batch.
// 4 waves (qw = q-frag). No staging: A-frags direct from L2-resident cT16.
__global__ __launch_bounds__(256, 4) void attn_lsum(
    const _Float16* __restrict__ qw16,
    const _Float16* __restrict__ cT16,
    float* __restrict__ lsum_ws)
{
  __shared__ float red[4][32];
  const int tid = threadIdx.x;
  const int qw  = tid >> 6;
  const int ln  = tid & 63;
  const int g   = ln >> 4;
  const int c16 = ln & 15;

  const int lin = blockIdx.x;
  const int b   = (lin & 7) >> 1;
  const int r2  = ((lin >> 3) << 1) | (lin & 1);  // 0..255
  const int otA = r2 >> 1;                        // 0..127
  const int qh  = r2 & 1;
  const int o0  = otA * 32;

  const _Float16* __restrict__ cbase = cT16 + (size_t)b * LSEQ * DDIM;

  f16x8 qb[2][8];
#pragma unroll
  for (int of = 0; of < 2; ++of)
#pragma unroll
    for (int kk = 0; kk < 8; ++kk)
      qb[of][kk] = *(const f16x8*)(qw16 +
          ((size_t)(b * LSEQ + o0 + of * 16 + c16) << 8) + kk * 32 + g * 8);

  float lsum0 = 0.f, lsum1 = 0.f;
  for (int t = 0; t < 32; ++t) {
    const int tq = qh * 32 + t;
    f16x8 aa[8];
    const _Float16* src = cbase + ((size_t)(tq * TQ + qw * 16 + c16) << 8) + g * 8;
#pragma unroll
    for (int kk = 0; kk < 8; ++kk) aa[kk] = *(const f16x8*)(src + kk * 32);
    f32x4 s0{0.f, 0.f, 0.f, 0.f}, s1{0.f, 0.f, 0.f, 0.f};
#pragma unroll
    for (int kk = 0; kk < 8; ++kk) {
      s0 = __builtin_amdgcn_mfma_f32_16x16x32_f16(aa[kk], qb[0][kk], s0, 0, 0, 0);
      s1 = __builtin_amdgcn_mfma_f32_16x16x32_f16(aa[kk], qb[1][kk], s1, 0, 0, 0);
    }
#pragma unroll
    for (int r = 0; r < 4; ++r) {
      lsum0 += __expf(s0[r]);
      lsum1 += __expf(s1[r]);
    }
  }
  lsum0 += __shfl_xor(lsum0, 16); lsum0 += __shfl_xor(lsum0, 32);
  lsum1 += __shfl_xor(lsum1, 16); lsum1 += __shfl_xor(lsum1, 32);
  if (ln < 16) {
    red[qw][ln]      = lsum0;
    red[qw][16 + ln] = lsum1;
  }
  __syncthreads();
  if (tid < 32)
    lsum_ws[((size_t)(b * 2 + qh)) * LSEQ + o0 + tid] =
        red[0][tid] + red[1][tid] + red[2][tid] + red[3][tid];
}

// ---------------- K2b: weights + PV -----------------------------------------
// 512 blocks: (ot 0..63 -> 64 o) x (qh -> 32 tiles) x batch; 8 waves (qw, oh).
// c_lds (q-major): byte = q*512 + d*2 ^ ((q&7)<<4). w_lds: o*128+q*2 ^ ((o&7)<<4).
__global__ __launch_bounds__(512, 4) void attn_pv(
    const _Float16* __restrict__ qw16,
    const _Float16* __restrict__ cT16,
    const _Float16* __restrict__ cD16,
    const float* __restrict__ lsum_ws,
    float* __restrict__ outp,
    float* __restrict__ wgt)
{
  __shared__ __align__(16) char smem[2][32768];  // c_lds dbuf; dead at epilogue
  __shared__ __align__(16) char wbuf[8192];      // w tile [64 o][64 q] f16 swz
  char* obuf = &smem[0][0];                      // epilogue alias (needs 64KB)

  const int tid = threadIdx.x;
  const int wv  = tid >> 6;
  const int qw  = wv & 3;
  const int oh  = wv >> 2;
  const int ln  = tid & 63;
  const int g   = ln >> 4;
  const int c16 = ln & 15;

  const int lin = blockIdx.x;
  const int b   = (lin & 7) >> 1;
  const int r2  = ((lin >> 3) << 1) | (lin & 1);  // 0..127
  const int ot  = r2 >> 1;                        // 0..63
  const int qh  = r2 & 1;
  const int o0  = ot * 64;
  const int bo  = b * LSEQ + o0;
  const int qbase = qh * (LSEQ / 2);

  const _Float16* __restrict__ cbase = cT16 + (size_t)b * LSEQ * DDIM;
  const _Float16* __restrict__ cDb   = cD16 + (size_t)b * DDIM * LSEQ;

  // invl from both q-half partial sums
  float invl[2];
#pragma unroll
  for (int of = 0; of < 2; ++of) {
    int o = o0 + oh * 32 + of * 16 + c16;
    invl[of] = 1.0f / (lsum_ws[(size_t)(b * 2) * LSEQ + o] +
                       lsum_ws[(size_t)(b * 2 + 1) * LSEQ + o]);
  }

  f16x8 qb[2][8];
#pragma unroll
  for (int of = 0; of < 2; ++of)
#pragma unroll
    for (int kk = 0; kk < 8; ++kk)
      qb[of][kk] = *(const f16x8*)(qw16 +
          ((size_t)(bo + oh * 32 + of * 16 + c16) << 8) + kk * 32 + g * 8);

  auto issue_dma = [&](int t, int pp) {
#pragma unroll
    for (int i = 0; i < 4; ++i) {
      unsigned x  = (unsigned)tid * 16 + i * 8192;
      unsigned q  = x >> 9;
      unsigned db = (x & 511u) ^ ((q & 7u) << 4);
      gld16(cbase + ((size_t)(qbase + t * TQ + q) << 8) + (db >> 1), &smem[pp][x]);
    }
  };

  f32x4 oacc[4][4];
#pragma unroll
  for (int m = 0; m < 4; ++m)
#pragma unroll
    for (int nf = 0; nf < 4; ++nf) oacc[m][nf] = f32x4{0.f, 0.f, 0.f, 0.f};

  int p = 0;
  issue_dma(0, 0);
  for (int t = 0; t < 32; ++t) {
    const int q0 = qbase + t * TQ;
    if (t == 0) asm volatile("s_waitcnt vmcnt(0)" ::: "memory");
    else        asm volatile("s_waitcnt vmcnt(2)" ::: "memory");
    __builtin_amdgcn_s_barrier();
    __builtin_amdgcn_sched_barrier(0);

    f16x8 bv[4];
#pragma unroll
    for (int nf = 0; nf < 4; ++nf)
      bv[nf] = *(const f16x8*)(cDb +
          ((size_t)(qw * 64 + nf * 16 + c16) << 12) + q0 + oh * 32 + g * 8);

    if (t < 31) issue_dma(t + 1, p ^ 1);

    const char* cl = smem[p];
    f32x4 sa0{0.f, 0.f, 0.f, 0.f}, sa1{0.f, 0.f, 0.f, 0.f};
#pragma unroll
    for (int kk = 0; kk < 8; ++kk) {
      unsigned off = (unsigned)((qw * 16 + c16) * 512 + kk * 64 + g * 16) ^
                     ((unsigned)(c16 & 7) << 4);
      f16x8 af = *(const f16x8*)(cl + off);
      sa0 = __builtin_amdgcn_mfma_f32_16x16x32_f16(af, qb[0][kk], sa0, 0, 0, 0);
      sa1 = __builtin_amdgcn_mfma_f32_16x16x32_f16(af, qb[1][kk], sa1, 0, 0, 0);
    }

#pragma unroll
    for (int of = 0; of < 2; ++of) {
      f32x4 sv = of ? sa1 : sa0;
      f32x4 wv4;
      f16x4 wh;
#pragma unroll
      for (int r = 0; r < 4; ++r) {
        float w = __expf(sv[r]) * invl[of];
        wv4[r] = w;
        wh[r]  = (_Float16)w;
      }
      int o = oh * 32 + of * 16 + c16;
      *(f32x4*)(wgt + ((size_t)(bo + o) << 12) + q0 + qw * 16 + 4 * g) = wv4;
      unsigned wb = (unsigned)(o * 128 + qw * 32 + g * 8) ^ ((unsigned)(o & 7) << 4);
      *(f16x4*)(wbuf + wb) = wh;
    }
    asm volatile("s_waitcnt lgkmcnt(0)" ::: "memory");
    __builtin_amdgcn_s_barrier();
    __builtin_amdgcn_sched_barrier(0);

#pragma unroll
    for (int m = 0; m < 4; ++m) {
      unsigned off = (unsigned)((m * 16 + c16) * 128 + oh * 64 + g * 16) ^
                     ((unsigned)(c16 & 7) << 4);
      f16x8 wa = *(const f16x8*)(wbuf + off);
#pragma unroll
      for (int nf = 0; nf < 4; ++nf)
        oacc[m][nf] =
            __builtin_amdgcn_mfma_f32_16x16x32_f16(wa, bv[nf], oacc[m][nf], 0, 0, 0);
    }
    p ^= 1;
  }

  // ---- cross-oh reduction via obuf (smem now dead), then atomicAdd to out
  __syncthreads();
  if (oh == 1) {
#pragma unroll
    for (int m = 0; m < 4; ++m)
#pragma unroll
      for (int nf = 0; nf < 4; ++nf)
        *(f32x4*)(obuf + qw * 16384 + (m * 4 + nf) * 1024 + ln * 16) = oacc[m][nf];
  }
  __syncthreads();
  if (oh == 0) {
#pragma unroll
    for (int m = 0; m < 4; ++m)
#pragma unroll
      for (int nf = 0; nf < 4; ++nf) {
        f32x4 o2 = *(const f32x4*)(obuf + qw * 16384 + (m * 4 + nf) * 1024 + ln * 16);
        f32x4 o  = oacc[m][nf] + o2;
#pragma unroll
        for (int r = 0; r < 4; ++r)
          atomicAdd(&outp[((size_t)(bo + m * 16 + 4 * g + r) << 8) +
                          qw * 64 + nf * 16 + c16], o[r]);
      }
  }
}

extern "C" void kernel_launch(void* const* d_in, const int* in_sizes, int n_in,
                              void* d_out, int out_size, void* d_ws, size_t ws_size,
                              hipStream_t stream) {
  const float* query   = (const float*)d_in[0];
  const float* context = (const float*)d_in[1];
  const float* W_in    = (const float*)d_in[2];
  const float* b_in    = (const float*)d_in[3];

  float* outp = (float*)d_out;
  float* wgt  = outp + (size_t)BATCH * LSEQ * DDIM;  // outputs concat: out, weights

  const size_t NELEM = (size_t)BATCH * LSEQ * DDIM;  // 4,194,304
  _Float16* qT16 = (_Float16*)d_ws;
  _Float16* cT16 = qT16 + NELEM;
  _Float16* qw16 = cT16 + NELEM;
  _Float16* W16  = qw16 + NELEM;           // +65536 halfs
  float*    lsum_ws = (float*)(W16 + 65536);  // 2*B*L f32 = 128KB; total ~25.4MB
  _Float16* cD16 = qT16;                   // aliases qT16 (dead after linear_q)

  transpose_cast<<<dim3(LSEQ / 64, DDIM / 64, 2 * BATCH), 256, 0, stream>>>(
      query, context, qT16, cT16);
  wconv<<<(DDIM * DDIM) / 1024, 256, 0, stream>>>(W_in, W16);
  linear_q<<<(BATCH * LSEQ) / 64, 256, 0, stream>>>(qT16, W16, b_in, qw16);
  castD<<<(int)(NELEM / 2048), 256, 0, stream>>>(context, cD16);
  hipMemsetAsync(outp, 0, NELEM * sizeof(float), stream);  // atomic target
  attn_lsum<<<1024, 256, 0, stream>>>(qw16, cT16, lsum_ws);
  attn_pv<<<512, 512, 0, stream>>>(qw16, cT16, cD16, lsum_ws, outp, wgt);
}

// Round 9
// 271.217 us; speedup vs baseline: 2.1801x; 2.1801x over previous
//
#include <hip/hip_runtime.h>

// Luong 'general' attention, B=4 D=256 L=4096.
// K0 transpose/cast q,c -> [B][L][D] f16 ; K0b W f32->f16 ; K1 linear qw=q@W^T+b ;
// K0c context cast [B][D][L] f32->f16 (aliases qT16, dead after K1).
// K2 attn_main (single fused kernel, 256 blocks lockstep = L2-locality-preserving):
//   swapped orientation S^T[q][o] = c[q,:]·qw[o,:].
//   phase A: scores from DMA-staged c_lds (dbuf), lsum += exp(s). STAGED (not
//            direct-L2): r7 showed direct streaming at 2 waves/SIMD exposes latency.
//   phase B: recompute s from c_lds (bit-identical), w=exp(s)*invl -> f32x4 wgt
//            + f16x4 w_lds; PV: A=w_lds b128, B direct from L2-hot cD16.
// LDS: 2x32KB c_lds + 8KB wbuf + 1KB redbuf = 73.75 KB (obuf aliases smem).
// ws usage: 25.3 MB.

#define BATCH 4
#define DDIM  256
#define LSEQ  4096
#define TQ    64

typedef float    f32x4 __attribute__((ext_vector_type(4)));
typedef _Float16 f16x8 __attribute__((ext_vector_type(8)));
typedef _Float16 f16x4 __attribute__((ext_vector_type(4)));

__device__ __forceinline__ void gld16(const void* g, void* l) {
  __builtin_amdgcn_global_load_lds((const __attribute__((address_space(1))) void*)g,
                                   (__attribute__((address_space(3))) void*)l, 16, 0, 0);
}

// ---------------- K0: [B][D][L] f32 -> [B][L][D] f16 (query & context) ------
__global__ __launch_bounds__(256) void transpose_cast(
    const float* __restrict__ q_in, const float* __restrict__ c_in,
    _Float16* __restrict__ q_out, _Float16* __restrict__ c_out)
{
  __shared__ float tile[64][68];
  const int which = blockIdx.z >> 2;
  const int b     = blockIdx.z & 3;
  const float* __restrict__ src = which ? c_in : q_in;
  _Float16* __restrict__ dst    = which ? c_out : q_out;
  const int l0 = blockIdx.x * 64, d0 = blockIdx.y * 64;
  const int tid = threadIdx.x;
  const int tr = tid >> 4, tc = (tid & 15) << 2;
#pragma unroll
  for (int i = 0; i < 4; ++i) {
    int d = tr + i * 16;
    f32x4 v = *(const f32x4*)(src + ((size_t)b * DDIM + d0 + d) * LSEQ + l0 + tc);
    *(f32x4*)&tile[d][tc] = v;
  }
  __syncthreads();
#pragma unroll
  for (int i = 0; i < 4; ++i) {
    int l = tr + i * 16;
    f16x4 h;
    h[0] = (_Float16)tile[tc + 0][l];
    h[1] = (_Float16)tile[tc + 1][l];
    h[2] = (_Float16)tile[tc + 2][l];
    h[3] = (_Float16)tile[tc + 3][l];
    *(f16x4*)(dst + ((size_t)b * LSEQ + l0 + l) * DDIM + d0 + tc) = h;
  }
}

// ---------------- K0b: W f32 -> f16 -----------------------------------------
__global__ __launch_bounds__(256) void wconv(const float* __restrict__ w,
                                             _Float16* __restrict__ w16) {
  int i = (blockIdx.x * 256 + threadIdx.x) * 4;
  f32x4 v = *(const f32x4*)(w + i);
  f16x4 h;
  h[0] = (_Float16)v[0]; h[1] = (_Float16)v[1];
  h[2] = (_Float16)v[2]; h[3] = (_Float16)v[3];
  *(f16x4*)(w16 + i) = h;
}

// ---------------- K0c: context [B][D][L] f32 -> f16 (same layout, pure cast)-
__global__ __launch_bounds__(256) void castD(const float* __restrict__ c_in,
                                             _Float16* __restrict__ cD16) {
  size_t i = ((size_t)blockIdx.x * 256 + threadIdx.x) * 8;
  f32x4 a = *(const f32x4*)(c_in + i);
  f32x4 b = *(const f32x4*)(c_in + i + 4);
  f16x8 h;
  h[0] = (_Float16)a[0]; h[1] = (_Float16)a[1];
  h[2] = (_Float16)a[2]; h[3] = (_Float16)a[3];
  h[4] = (_Float16)b[0]; h[5] = (_Float16)b[1];
  h[6] = (_Float16)b[2]; h[7] = (_Float16)b[3];
  *(f16x8*)(cD16 + i) = h;
}

// ---------------- K1: qw16 = qT16 @ W^T + bias ------------------------------
__global__ __launch_bounds__(256) void linear_q(
    const _Float16* __restrict__ qT16, const _Float16* __restrict__ W16,
    const float* __restrict__ bias, _Float16* __restrict__ qw16)
{
  const int tid = threadIdx.x;
  const int wv = tid >> 6, ln = tid & 63, g = ln >> 4, c16 = ln & 15;
  const size_t r0 = (size_t)blockIdx.x * 64 + wv * 16;

  f16x8 qa[8];
  const _Float16* qrow = qT16 + (r0 + c16) * DDIM + g * 8;
#pragma unroll
  for (int kk = 0; kk < 8; ++kk) qa[kk] = *(const f16x8*)(qrow + kk * 32);

  f32x4 acc[16];
#pragma unroll
  for (int n = 0; n < 16; ++n) acc[n] = f32x4{0.f, 0.f, 0.f, 0.f};

#pragma unroll 2
  for (int kk = 0; kk < 8; ++kk) {
#pragma unroll
    for (int n = 0; n < 16; ++n) {
      f16x8 bf = *(const f16x8*)(W16 + (n * 16 + c16) * DDIM + kk * 32 + g * 8);
      acc[n] = __builtin_amdgcn_mfma_f32_16x16x32_f16(qa[kk], bf, acc[n], 0, 0, 0);
    }
  }
#pragma unroll
  for (int n = 0; n < 16; ++n) {
    float bb = bias[n * 16 + c16];
#pragma unroll
    for (int r = 0; r < 4; ++r)
      qw16[(r0 + 4 * g + r) * DDIM + n * 16 + c16] = (_Float16)(acc[n][r] + bb);
  }
}

// ---------------- K2: fused attention ---------------------------------------
// c_lds (q-major): byte = q*512 + d*2 ^ ((q&7)<<4); scores-A read b128:
//   off=(qw*16+c16)*512+kk*64+g*16 ^ ((c16&7)<<4)  (2-way floor).
// wbuf [o][q]: byte = o*128 + q*2 ^ ((o&7)<<4); write f16x4, PV-A read b128.
// DMA: linear LDS dest + inverse-swizzled global source (rule #21).
__global__ __launch_bounds__(512) void attn_main(
    const _Float16* __restrict__ qw16,
    const _Float16* __restrict__ cT16,
    const _Float16* __restrict__ cD16,
    float* __restrict__ outp,
    float* __restrict__ wgt)
{
  __shared__ __align__(16) char smem[2][32768];  // c_lds double buffer
  __shared__ __align__(16) char wbuf[8192];      // w tile [64 o][64 q] f16 swz
  __shared__ float redbuf[4][64];                // per-qw row sums
  char* obuf = &smem[0][0];                      // epilogue alias (64KB, dead)

  const int tid = threadIdx.x;
  const int wv  = tid >> 6;       // 0..7
  const int qw  = wv & 3;         // scores q-frag / PV d-slice
  const int oh  = wv >> 2;        // scores o-half / PV k-half
  const int ln  = tid & 63;
  const int g   = ln >> 4;
  const int c16 = ln & 15;

  // batch -> XCD-pair remap (context 2MB/batch stays L2-resident under lockstep)
  const int lin   = blockIdx.y * 64 + blockIdx.x;
  const int b     = (lin & 7) >> 1;
  const int otile = ((lin >> 3) << 1) | (lin & 1);
  const int o0    = otile * 64;
  const int bo    = b * LSEQ + o0;

  const _Float16* __restrict__ cbase = cT16 + (size_t)b * LSEQ * DDIM;
  const _Float16* __restrict__ cDb   = cD16 + (size_t)b * DDIM * LSEQ;

  // B-frags (qw rows as B operand): o = oh*32 + of*16 + c16, k = kk*32+g*8..
  f16x8 qb[2][8];
#pragma unroll
  for (int of = 0; of < 2; ++of)
#pragma unroll
    for (int kk = 0; kk < 8; ++kk)
      qb[of][kk] = *(const f16x8*)(qw16 +
          ((size_t)(bo + oh * 32 + of * 16 + c16) << 8) + kk * 32 + g * 8);

  auto issue_dma = [&](int t, int pp) {
#pragma unroll
    for (int i = 0; i < 4; ++i) {
      unsigned x  = (unsigned)tid * 16 + i * 8192;
      unsigned q  = x >> 9;
      unsigned db = (x & 511u) ^ ((q & 7u) << 4);
      gld16(cbase + ((size_t)(t * TQ + q) << 8) + (db >> 1), &smem[pp][x]);
    }
  };

  // ---- phase A: staged scores, lsum += exp(s) ----
  float lsum0 = 0.f, lsum1 = 0.f;
  int p = 0;
  issue_dma(0, 0);
  for (int t = 0; t < LSEQ / TQ; ++t) {
    asm volatile("s_waitcnt vmcnt(0)" ::: "memory");
    __builtin_amdgcn_s_barrier();
    issue_dma(t < LSEQ / TQ - 1 ? t + 1 : 0, p ^ 1);  // t=63 stages B's tile 0
    __builtin_amdgcn_sched_barrier(0);

    const char* cl = smem[p];
    f32x4 sa0{0.f, 0.f, 0.f, 0.f}, sa1{0.f, 0.f, 0.f, 0.f};
#pragma unroll
    for (int kk = 0; kk < 8; ++kk) {
      unsigned off = (unsigned)((qw * 16 + c16) * 512 + kk * 64 + g * 16) ^
                     ((unsigned)(c16 & 7) << 4);
      f16x8 af = *(const f16x8*)(cl + off);
      sa0 = __builtin_amdgcn_mfma_f32_16x16x32_f16(af, qb[0][kk], sa0, 0, 0, 0);
      sa1 = __builtin_amdgcn_mfma_f32_16x16x32_f16(af, qb[1][kk], sa1, 0, 0, 0);
    }
#pragma unroll
    for (int r = 0; r < 4; ++r) {
      lsum0 += __expf(sa0[r]);
      lsum1 += __expf(sa1[r]);
    }
    p ^= 1;
  }

  // reduce over g (lanes 16.. hold other q rows of same o-col)
  lsum0 += __shfl_xor(lsum0, 16); lsum0 += __shfl_xor(lsum0, 32);
  lsum1 += __shfl_xor(lsum1, 16); lsum1 += __shfl_xor(lsum1, 32);
  if (ln < 16) {
    redbuf[qw][oh * 32 + ln]      = lsum0;
    redbuf[qw][oh * 32 + 16 + ln] = lsum1;
  }
  __syncthreads();
  float invl[2];
#pragma unroll
  for (int of = 0; of < 2; ++of) {
    int o = oh * 32 + of * 16 + c16;
    invl[of] = 1.0f / (redbuf[0][o] + redbuf[1][o] + redbuf[2][o] + redbuf[3][o]);
  }

  // ---- phase B: staged scores (bit-identical), weights out, PV ----
  f32x4 oacc[4][4];
#pragma unroll
  for (int m = 0; m < 4; ++m)
#pragma unroll
    for (int nf = 0; nf < 4; ++nf) oacc[m][nf] = f32x4{0.f, 0.f, 0.f, 0.f};

  for (int t = 0; t < LSEQ / TQ; ++t) {
    const int q0 = t * TQ;
    if (t == 0) asm volatile("s_waitcnt vmcnt(0)" ::: "memory");
    else        asm volatile("s_waitcnt vmcnt(2)" ::: "memory");
    __builtin_amdgcn_s_barrier();
    __builtin_amdgcn_sched_barrier(0);

    // PV B-frags for this tile, direct from L2-hot cD16
    f16x8 bv[4];
#pragma unroll
    for (int nf = 0; nf < 4; ++nf)
      bv[nf] = *(const f16x8*)(cDb +
          ((size_t)(qw * 64 + nf * 16 + c16) << 12) + q0 + oh * 32 + g * 8);

    if (t < LSEQ / TQ - 1) issue_dma(t + 1, p ^ 1);

    const char* cl = smem[p];
    f32x4 sa0{0.f, 0.f, 0.f, 0.f}, sa1{0.f, 0.f, 0.f, 0.f};
#pragma unroll
    for (int kk = 0; kk < 8; ++kk) {
      unsigned off = (unsigned)((qw * 16 + c16) * 512 + kk * 64 + g * 16) ^
                     ((unsigned)(c16 & 7) << 4);
      f16x8 af = *(const f16x8*)(cl + off);
      sa0 = __builtin_amdgcn_mfma_f32_16x16x32_f16(af, qb[0][kk], sa0, 0, 0, 0);
      sa1 = __builtin_amdgcn_mfma_f32_16x16x32_f16(af, qb[1][kk], sa1, 0, 0, 0);
    }

    // weights: lane holds o = oh*32+of*16+c16, q = q0+qw*16+4g+r (contig r)
#pragma unroll
    for (int of = 0; of < 2; ++of) {
      f32x4 sv = of ? sa1 : sa0;
      f32x4 wv4;
      f16x4 wh;
#pragma unroll
      for (int r = 0; r < 4; ++r) {
        float w = __expf(sv[r]) * invl[of];
        wv4[r] = w;
        wh[r]  = (_Float16)w;
      }
      int o = oh * 32 + of * 16 + c16;
      *(f32x4*)(wgt + ((size_t)(bo + o) << 12) + q0 + qw * 16 + 4 * g) = wv4;
      unsigned wb = (unsigned)(o * 128 + qw * 32 + g * 8) ^ ((unsigned)(o & 7) << 4);
      *(f16x4*)(wbuf + wb) = wh;
    }
    asm volatile("s_waitcnt lgkmcnt(0)" ::: "memory");
    __builtin_amdgcn_s_barrier();
    __builtin_amdgcn_sched_barrier(0);

    // PV: A = w_lds rows (o), k = q-half oh; B = bv; out d-slice qw
#pragma unroll
    for (int m = 0; m < 4; ++m) {
      unsigned off = (unsigned)((m * 16 + c16) * 128 + oh * 64 + g * 16) ^
                     ((unsigned)(c16 & 7) << 4);
      f16x8 wa = *(const f16x8*)(wbuf + off);
#pragma unroll
      for (int nf = 0; nf < 4; ++nf)
        oacc[m][nf] =
            __builtin_amdgcn_mfma_f32_16x16x32_f16(wa, bv[nf], oacc[m][nf], 0, 0, 0);
    }
    p ^= 1;
  }

  // ---- cross-oh reduction via obuf (smem dead), then store out
  __syncthreads();
  if (oh == 1) {
#pragma unroll
    for (int m = 0; m < 4; ++m)
#pragma unroll
      for (int nf = 0; nf < 4; ++nf)
        *(f32x4*)(obuf + qw * 16384 + (m * 4 + nf) * 1024 + ln * 16) = oacc[m][nf];
  }
  __syncthreads();
  if (oh == 0) {
#pragma unroll
    for (int m = 0; m < 4; ++m)
#pragma unroll
      for (int nf = 0; nf < 4; ++nf) {
        f32x4 o2 = *(const f32x4*)(obuf + qw * 16384 + (m * 4 + nf) * 1024 + ln * 16);
        f32x4 o  = oacc[m][nf] + o2;
#pragma unroll
        for (int r = 0; r < 4; ++r)
          outp[((size_t)(bo + m * 16 + 4 * g + r) << 8) + qw * 64 + nf * 16 + c16] = o[r];
      }
  }
}

extern "C" void kernel_launch(void* const* d_in, const int* in_sizes, int n_in,
                              void* d_out, int out_size, void* d_ws, size_t ws_size,
                              hipStream_t stream) {
  const float* query   = (const float*)d_in[0];
  const float* context = (const float*)d_in[1];
  const float* W_in    = (const float*)d_in[2];
  const float* b_in    = (const float*)d_in[3];

  float* outp = (float*)d_out;
  float* wgt  = outp + (size_t)BATCH * LSEQ * DDIM;  // outputs concat: out, weights

  const size_t NELEM = (size_t)BATCH * LSEQ * DDIM;  // 4,194,304
  _Float16* qT16 = (_Float16*)d_ws;
  _Float16* cT16 = qT16 + NELEM;
  _Float16* qw16 = cT16 + NELEM;
  _Float16* W16  = qw16 + NELEM;   // +65536 halfs; total ws use = 25.3 MB
  _Float16* cD16 = qT16;           // aliases qT16 (dead after linear_q)

  transpose_cast<<<dim3(LSEQ / 64, DDIM / 64, 2 * BATCH), 256, 0, stream>>>(
      query, context, qT16, cT16);
  wconv<<<(DDIM * DDIM) / 1024, 256, 0, stream>>>(W_in, W16);
  linear_q<<<(BATCH * LSEQ) / 64, 256, 0, stream>>>(qT16, W16, b_in, qw16);
  castD<<<(int)(NELEM / 2048), 256, 0, stream>>>(context, cD16);
  attn_main<<<dim3(64, BATCH), 512, 0, stream>>>(qw16, cT16, cD16, outp, wgt);
}

// Round 10
// 266.712 us; speedup vs baseline: 2.2170x; 1.0169x over previous
//
#include <hip/hip_runtime.h>

// Luong 'general' attention, B=4 D=256 L=4096.
// K0 transpose/cast q,c -> [B][L][D] f16 (+ fused cD16 f16 cast of context in
//     original [B][D][L] layout) ; K0b W f32->f16 ; K1 linear qw=q@W^T+b.
// K2 attn_main: 256 blocks lockstep (L2-locality), 1024 thr = 16 waves
//     (4 waves/SIMD — occupancy from inside the block; r8 showed more blocks
//     breaks lockstep L2 reuse: FETCH 29MB -> 1GB).
//   swapped orientation S^T[q][o] = c[q,:]·qw[o,:].
//   phase A: scores from DMA-staged c_lds (dbuf), lsum += exp(s).
//   phase B: recompute s (bit-identical), w=exp(s)*invl -> f32x4 wgt + f16x4
//            w_lds; PV: A=w_lds b128 (wave=(dw,kh)), B direct from L2-hot cD16.
// LDS: 2x32KB c_lds + 8KB wbuf + 1KB redbuf = 73.75 KB (obuf aliases smem).
// ws usage: 25.3 MB.

#define BATCH 4
#define DDIM  256
#define LSEQ  4096
#define TQ    64

typedef float    f32x4 __attribute__((ext_vector_type(4)));
typedef _Float16 f16x8 __attribute__((ext_vector_type(8)));
typedef _Float16 f16x4 __attribute__((ext_vector_type(4)));

__device__ __forceinline__ void gld16(const void* g, void* l) {
  __builtin_amdgcn_global_load_lds((const __attribute__((address_space(1))) void*)g,
                                   (__attribute__((address_space(3))) void*)l, 16, 0, 0);
}

// ---------------- K0: [B][D][L] f32 -> [B][L][D] f16 (+ cD16 for context) ---
__global__ __launch_bounds__(256) void transpose_cast(
    const float* __restrict__ q_in, const float* __restrict__ c_in,
    _Float16* __restrict__ q_out, _Float16* __restrict__ c_out,
    _Float16* __restrict__ cD16)
{
  __shared__ float tile[64][68];
  const int which = blockIdx.z >> 2;
  const int b     = blockIdx.z & 3;
  const float* __restrict__ src = which ? c_in : q_in;
  _Float16* __restrict__ dst    = which ? c_out : q_out;
  const int l0 = blockIdx.x * 64, d0 = blockIdx.y * 64;
  const int tid = threadIdx.x;
  const int tr = tid >> 4, tc = (tid & 15) << 2;
#pragma unroll
  for (int i = 0; i < 4; ++i) {
    int d = tr + i * 16;
    f32x4 v = *(const f32x4*)(src + ((size_t)b * DDIM + d0 + d) * LSEQ + l0 + tc);
    *(f32x4*)&tile[d][tc] = v;
    if (which) {  // fused: context f16 cast, original [B][D][L] layout
      f16x4 h;
      h[0] = (_Float16)v[0]; h[1] = (_Float16)v[1];
      h[2] = (_Float16)v[2]; h[3] = (_Float16)v[3];
      *(f16x4*)(cD16 + ((size_t)b * DDIM + d0 + d) * LSEQ + l0 + tc) = h;
    }
  }
  __syncthreads();
#pragma unroll
  for (int i = 0; i < 4; ++i) {
    int l = tr + i * 16;
    f16x4 h;
    h[0] = (_Float16)tile[tc + 0][l];
    h[1] = (_Float16)tile[tc + 1][l];
    h[2] = (_Float16)tile[tc + 2][l];
    h[3] = (_Float16)tile[tc + 3][l];
    *(f16x4*)(dst + ((size_t)b * LSEQ + l0 + l) * DDIM + d0 + tc) = h;
  }
}

// ---------------- K0b: W f32 -> f16 -----------------------------------------
__global__ __launch_bounds__(256) void wconv(const float* __restrict__ w,
                                             _Float16* __restrict__ w16) {
  int i = (blockIdx.x * 256 + threadIdx.x) * 4;
  f32x4 v = *(const f32x4*)(w + i);
  f16x4 h;
  h[0] = (_Float16)v[0]; h[1] = (_Float16)v[1];
  h[2] = (_Float16)v[2]; h[3] = (_Float16)v[3];
  *(f16x4*)(w16 + i) = h;
}

// ---------------- K1: qw16 = qT16 @ W^T + bias ------------------------------
__global__ __launch_bounds__(256) void linear_q(
    const _Float16* __restrict__ qT16, const _Float16* __restrict__ W16,
    const float* __restrict__ bias, _Float16* __restrict__ qw16)
{
  const int tid = threadIdx.x;
  const int wv = tid >> 6, ln = tid & 63, g = ln >> 4, c16 = ln & 15;
  const size_t r0 = (size_t)blockIdx.x * 64 + wv * 16;

  f16x8 qa[8];
  const _Float16* qrow = qT16 + (r0 + c16) * DDIM + g * 8;
#pragma unroll
  for (int kk = 0; kk < 8; ++kk) qa[kk] = *(const f16x8*)(qrow + kk * 32);

  f32x4 acc[16];
#pragma unroll
  for (int n = 0; n < 16; ++n) acc[n] = f32x4{0.f, 0.f, 0.f, 0.f};

#pragma unroll 2
  for (int kk = 0; kk < 8; ++kk) {
#pragma unroll
    for (int n = 0; n < 16; ++n) {
      f16x8 bf = *(const f16x8*)(W16 + (n * 16 + c16) * DDIM + kk * 32 + g * 8);
      acc[n] = __builtin_amdgcn_mfma_f32_16x16x32_f16(qa[kk], bf, acc[n], 0, 0, 0);
    }
  }
#pragma unroll
  for (int n = 0; n < 16; ++n) {
    float bb = bias[n * 16 + c16];
#pragma unroll
    for (int r = 0; r < 4; ++r)
      qw16[(r0 + 4 * g + r) * DDIM + n * 16 + c16] = (_Float16)(acc[n][r] + bb);
  }
}

// ---------------- K2: fused attention (16 waves) ----------------------------
// c_lds (q-major): byte = q*512 + d*2 ^ ((q&7)<<4); scores-A read b128:
//   off=(qw*16+c16)*512+kk*64+g*16 ^ ((c16&7)<<4)  (2-way floor).
// wbuf [o][q]: byte = o*128 + q*2 ^ ((o&7)<<4); write f16x4, PV-A read b128.
// DMA: linear LDS dest + inverse-swizzled global source (rule #21).
__global__ __launch_bounds__(1024, 4) void attn_main(
    const _Float16* __restrict__ qw16,
    const _Float16* __restrict__ cT16,
    const _Float16* __restrict__ cD16,
    float* __restrict__ outp,
    float* __restrict__ wgt)
{
  __shared__ __align__(16) char smem[2][32768];  // c_lds double buffer
  __shared__ __align__(16) char wbuf[8192];      // w tile [64 o][64 q] f16 swz
  __shared__ float redbuf[4][64];                // per-qw row sums
  char* obuf = &smem[0][0];                      // epilogue alias (64KB, dead)

  const int tid = threadIdx.x;
  const int wv  = tid >> 6;       // 0..15
  const int qw  = wv & 3;         // scores q-frag
  const int ow  = wv >> 2;        // scores o-frag (16 o each)
  const int kh  = wv & 1;         // PV k-half (32 q)
  const int dw  = wv >> 1;        // PV d-slice (32 d)
  const int ln  = tid & 63;
  const int g   = ln >> 4;
  const int c16 = ln & 15;

  // batch -> XCD-pair remap (context 2MB/batch stays L2-resident under lockstep)
  const int lin   = blockIdx.y * 64 + blockIdx.x;
  const int b     = (lin & 7) >> 1;
  const int otile = ((lin >> 3) << 1) | (lin & 1);
  const int o0    = otile * 64;
  const int bo    = b * LSEQ + o0;

  const _Float16* __restrict__ cbase = cT16 + (size_t)b * LSEQ * DDIM;
  const _Float16* __restrict__ cDb   = cD16 + (size_t)b * DDIM * LSEQ;

  // B-frags (qw rows as B operand): o = ow*16 + c16, k = kk*32 + g*8..
  f16x8 qb[8];
#pragma unroll
  for (int kk = 0; kk < 8; ++kk)
    qb[kk] = *(const f16x8*)(qw16 +
        ((size_t)(bo + ow * 16 + c16) << 8) + kk * 32 + g * 8);

  auto issue_dma = [&](int t, int pp) {
#pragma unroll
    for (int i = 0; i < 2; ++i) {
      unsigned x  = (unsigned)tid * 16 + i * 16384;
      unsigned q  = x >> 9;
      unsigned db = (x & 511u) ^ ((q & 7u) << 4);
      gld16(cbase + ((size_t)(t * TQ + q) << 8) + (db >> 1), &smem[pp][x]);
    }
  };

  // ---- phase A: staged scores, lsum += exp(s) ----
  float lsum = 0.f;
  int p = 0;
  issue_dma(0, 0);
  for (int t = 0; t < LSEQ / TQ; ++t) {
    asm volatile("s_waitcnt vmcnt(0)" ::: "memory");
    __builtin_amdgcn_s_barrier();
    issue_dma(t < LSEQ / TQ - 1 ? t + 1 : 0, p ^ 1);  // t=63 stages B's tile 0
    __builtin_amdgcn_sched_barrier(0);

    const char* cl = smem[p];
    f32x4 sa{0.f, 0.f, 0.f, 0.f};
#pragma unroll
    for (int kk = 0; kk < 8; ++kk) {
      unsigned off = (unsigned)((qw * 16 + c16) * 512 + kk * 64 + g * 16) ^
                     ((unsigned)(c16 & 7) << 4);
      f16x8 af = *(const f16x8*)(cl + off);
      sa = __builtin_amdgcn_mfma_f32_16x16x32_f16(af, qb[kk], sa, 0, 0, 0);
    }
#pragma unroll
    for (int r = 0; r < 4; ++r) lsum += __expf(sa[r]);
    p ^= 1;
  }

  // reduce over g (lanes 16.. hold other q rows of same o-col)
  lsum += __shfl_xor(lsum, 16);
  lsum += __shfl_xor(lsum, 32);
  if (ln < 16) redbuf[qw][ow * 16 + ln] = lsum;
  __syncthreads();
  const int o_mine = ow * 16 + c16;
  const float invl = 1.0f / (redbuf[0][o_mine] + redbuf[1][o_mine] +
                             redbuf[2][o_mine] + redbuf[3][o_mine]);

  // ---- phase B: staged scores (bit-identical), weights out, PV ----
  f32x4 oacc[4][2];
#pragma unroll
  for (int m = 0; m < 4; ++m)
#pragma unroll
    for (int nf = 0; nf < 2; ++nf) oacc[m][nf] = f32x4{0.f, 0.f, 0.f, 0.f};

  for (int t = 0; t < LSEQ / TQ; ++t) {
    const int q0 = t * TQ;
    if (t == 0) asm volatile("s_waitcnt vmcnt(0)" ::: "memory");
    else        asm volatile("s_waitcnt vmcnt(1)" ::: "memory");
    __builtin_amdgcn_s_barrier();
    __builtin_amdgcn_sched_barrier(0);

    // PV B-frags for this tile, direct from L2-hot cD16 (before DMA issue)
    f16x8 bv[2];
#pragma unroll
    for (int nf = 0; nf < 2; ++nf)
      bv[nf] = *(const f16x8*)(cDb +
          ((size_t)(dw * 32 + nf * 16 + c16) << 12) + q0 + kh * 32 + g * 8);

    if (t < LSEQ / TQ - 1) issue_dma(t + 1, p ^ 1);

    const char* cl = smem[p];
    f32x4 sa{0.f, 0.f, 0.f, 0.f};
#pragma unroll
    for (int kk = 0; kk < 8; ++kk) {
      unsigned off = (unsigned)((qw * 16 + c16) * 512 + kk * 64 + g * 16) ^
                     ((unsigned)(c16 & 7) << 4);
      f16x8 af = *(const f16x8*)(cl + off);
      sa = __builtin_amdgcn_mfma_f32_16x16x32_f16(af, qb[kk], sa, 0, 0, 0);
    }

    // weights: lane holds o = ow*16+c16, q = q0+qw*16+4g+r (contig r)
    {
      f32x4 wv4;
      f16x4 wh;
#pragma unroll
      for (int r = 0; r < 4; ++r) {
        float w = __expf(sa[r]) * invl;
        wv4[r] = w;
        wh[r]  = (_Float16)w;
      }
      *(f32x4*)(wgt + ((size_t)(bo + o_mine) << 12) + q0 + qw * 16 + 4 * g) = wv4;
      unsigned wb = (unsigned)(o_mine * 128 + (qw * 16 + 4 * g) * 2) ^
                    ((unsigned)(o_mine & 7) << 4);
      *(f16x4*)(wbuf + wb) = wh;
    }
    asm volatile("s_waitcnt lgkmcnt(0)" ::: "memory");
    __builtin_amdgcn_s_barrier();
    __builtin_amdgcn_sched_barrier(0);

    // PV: A = w_lds rows (o), k-half kh; B = bv; out d-slice dw
#pragma unroll
    for (int m = 0; m < 4; ++m) {
      unsigned off = (unsigned)((m * 16 + c16) * 128 + kh * 64 + g * 16) ^
                     ((unsigned)(c16 & 7) << 4);
      f16x8 wa = *(const f16x8*)(wbuf + off);
#pragma unroll
      for (int nf = 0; nf < 2; ++nf)
        oacc[m][nf] =
            __builtin_amdgcn_mfma_f32_16x16x32_f16(wa, bv[nf], oacc[m][nf], 0, 0, 0);
    }
    p ^= 1;
  }

  // ---- cross-kh reduction via obuf (smem dead), then store out
  __syncthreads();
  if (kh == 1) {
#pragma unroll
    for (int m = 0; m < 4; ++m)
#pragma unroll
      for (int nf = 0; nf < 2; ++nf)
        *(f32x4*)(obuf + dw * 8192 + (m * 2 + nf) * 1024 + ln * 16) = oacc[m][nf];
  }
  __syncthreads();
  if (kh == 0) {
#pragma unroll
    for (int m = 0; m < 4; ++m)
#pragma unroll
      for (int nf = 0; nf < 2; ++nf) {
        f32x4 o2 = *(const f32x4*)(obuf + dw * 8192 + (m * 2 + nf) * 1024 + ln * 16);
        f32x4 o  = oacc[m][nf] + o2;
#pragma unroll
        for (int r = 0; r < 4; ++r)
          outp[((size_t)(bo + m * 16 + 4 * g + r) << 8) + dw * 32 + nf * 16 + c16] = o[r];
      }
  }
}

extern "C" void kernel_launch(void* const* d_in, const int* in_sizes, int n_in,
                              void* d_out, int out_size, void* d_ws, size_t ws_size,
                              hipStream_t stream) {
  const float* query   = (const float*)d_in[0];
  const float* context = (const float*)d_in[1];
  const float* W_in    = (const float*)d_in[2];
  const float* b_in    = (const float*)d_in[3];

  float* outp = (float*)d_out;
  float* wgt  = outp + (size_t)BATCH * LSEQ * DDIM;  // outputs concat: out, weights

  const size_t NELEM = (size_t)BATCH * LSEQ * DDIM;  // 4,194,304
  _Float16* qT16 = (_Float16*)d_ws;
  _Float16* cT16 = qT16 + NELEM;
  _Float16* qw16 = cT16 + NELEM;
  _Float16* W16  = qw16 + NELEM;   // +65536 halfs
  _Float16* cD16 = W16 + 65536;    // context f16, [B][D][L]; total ws ~33.7 MB

  transpose_cast<<<dim3(LSEQ / 64, DDIM / 64, 2 * BATCH), 256, 0, stream>>>(
      query, context, qT16, cT16, cD16);
  wconv<<<(DDIM * DDIM) / 1024, 256, 0, stream>>>(W_in, W16);
  linear_q<<<(BATCH * LSEQ) / 64, 256, 0, stream>>>(qT16, W16, b_in, qw16);
  attn_main<<<dim3(64, BATCH), 1024, 0, stream>>>(qw16, cT16, cD16, outp, wgt);
}